// Round 4
// baseline (287.967 us; speedup 1.0000x reference)
//
#include <hip/hip_runtime.h>
#include <math.h>

#define BB 64
#define T_SUB 512
#define WW 256
#define DD 768
#define HH 20
#define CAP_DIM 10
#define IN_DIM 778
#define KPAD 800
#define G4 80     // 4*H
#define NOUT 160  // both directions fused

typedef _Float16 f16x8 __attribute__((ext_vector_type(8)));
typedef float f32x4 __attribute__((ext_vector_type(4)));

// ws layout (bytes):
//   wpad : [160][800] f16   @ 0        (256,000 B)
//   seg  : int2[16384]      @ 256,000  (131,072 B)
//   gpre : [16384][160] f32 @ 387,072  (10,485,760 B)  -- columns PERMUTED (see below)
#define WP_OFF   ((size_t)0)
#define SEG_OFF  ((size_t)256000)
#define GP_OFF   ((size_t)387072)

// ---------------- K0a: pad + fuse input-projection weights -> fp16 ----------
__global__ __launch_bounds__(256) void k_pad_w(
    const float* __restrict__ wf, const float* __restrict__ wb,
    _Float16* __restrict__ wp)
{
    int j = blockIdx.x;  // 0..159
    const float* src = (j < G4) ? (wf + (size_t)j * IN_DIM)
                                : (wb + (size_t)(j - G4) * IN_DIM);
    for (int k = threadIdx.x; k < KPAD; k += 256)
        wp[(size_t)j * KPAD + k] = (k < IN_DIM) ? (_Float16)src[k] : (_Float16)0.f;
}

// ---------------- K0b: all word-segment binary searches, one thread each ----
__global__ __launch_bounds__(256) void k_seg(
    const int* __restrict__ b2t, int2* __restrict__ seg)
{
    int b = blockIdx.x, w = threadIdx.x;
    const int* row = b2t + (size_t)b * T_SUB;
    int lo = 0, hi = T_SUB;
    while (lo < hi) { int m = (lo + hi) >> 1; if (row[m] < w) lo = m + 1; else hi = m; }
    int lo2 = lo, hi2 = T_SUB;
    while (lo2 < hi2) { int m = (lo2 + hi2) >> 1; if (row[m] < w + 1) lo2 = m + 1; else hi2 = m; }
    seg[(size_t)b * WW + w] = make_int2(lo, lo2 - lo);
}

// ---------------- K1: fused {layer-mean + word-mean + cap concat} + MFMA GEMM
// Block = 32 output rows (words of one batch), 256 threads, grid 512 (2/CU).
// Phase 1: stream hiddens -> word means -> fp16 LDS A-tile [32][808].
// Phase 2: K-loop, stage W tile [160][40], mfma_f32_16x16x32_f16.
// C-write permutes columns so lstm lane j reads (gate j, gate j+40) as float2:
//   col (dir*80 + g) -> dir*80 + (g%40)*2 + g/40
#define BMF 32
__global__ __launch_bounds__(256) void k_fused(
    const float* __restrict__ hiddens, const int2* __restrict__ seg,
    const int* __restrict__ cap_inds, const float* __restrict__ cap_table,
    const _Float16* __restrict__ wp, float* __restrict__ gpre)
{
    __shared__ _Float16 As[BMF][808];   // 808 f16 row stride: b128-aligned, <=2-way banks
    __shared__ _Float16 Ws[NOUT][40];
    __shared__ int lo_s[BMF], cnt_s[BMF];
    int t = threadIdx.x;
    int row0 = blockIdx.x * BMF;
    int b = row0 >> 8, w0 = row0 & 255;

    if (t < BMF) { int2 s = seg[(size_t)b * WW + w0 + t]; lo_s[t] = s.x; cnt_s[t] = s.y; }
    __syncthreads();

    // ---- phase 1: word means (threads 0..191 own 4 dims each) ----
    const size_t LSTR = (size_t)BB * (T_SUB + 1) * DD;
    if (t < 192) {
        const float* hb = hiddens + (size_t)b * (T_SUB + 1) * DD + t * 4;
        for (int w = 0; w < BMF; ++w) {
            int lo = lo_s[w], cnt = cnt_s[w];
            float inv = 1.0f / (3.0f * (float)(cnt > 0 ? cnt : 1));
            float ax = 0.f, ay = 0.f, az = 0.f, aw = 0.f;
            for (int l = 0; l < 3; ++l) {
                const float* base = hb + l * LSTR;
                for (int ti = 0; ti < cnt; ++ti) {
                    float4 v = *(const float4*)(base + (size_t)(lo + ti + 1) * DD);
                    ax += v.x; ay += v.y; az += v.z; aw += v.w;
                }
            }
            As[w][t * 4 + 0] = (_Float16)(ax * inv);
            As[w][t * 4 + 1] = (_Float16)(ay * inv);
            As[w][t * 4 + 2] = (_Float16)(az * inv);
            As[w][t * 4 + 3] = (_Float16)(aw * inv);
        }
    }
    // cap embedding cols 768..777, zero pad 778..807
    for (int s = t; s < BMF * 40; s += 256) {
        int w = s / 40, c = s % 40;
        float v = 0.f;
        if (c < CAP_DIM) {
            int ci = cap_inds[(size_t)b * WW + w0 + w];
            v = cap_table[ci * CAP_DIM + c];
        }
        As[w][DD + c] = (_Float16)v;
    }

    // ---- phase 2: MFMA K-loop ----
    int wv = t >> 6, lane = t & 63;
    int mrow  = (wv & 1) * 16 + (lane & 15);
    int nbase = (wv >> 1) * 80;          // waves {0,1}: cols 0..79; {2,3}: 80..159
    int koff  = (lane >> 4) * 8;
    f32x4 acc[5];
#pragma unroll
    for (int i = 0; i < 5; i++)
#pragma unroll
        for (int r = 0; r < 4; r++) acc[i][r] = 0.f;

    for (int k0 = 0; k0 < KPAD; k0 += 32) {
        __syncthreads();                  // also covers phase-1 As writes (first iter)
        for (int s2 = t; s2 < 640; s2 += 256) {
            int r = s2 >> 2, ch = s2 & 3;
            float4 v = *(const float4*)(wp + (size_t)r * KPAD + k0 + ch * 8);
            *(float4*)(&Ws[r][ch * 8]) = v;
        }
        __syncthreads();
        f16x8 afrag = *(const f16x8*)(&As[mrow][k0 + koff]);
#pragma unroll
        for (int nf = 0; nf < 5; nf++) {
            f16x8 bfrag = *(const f16x8*)(&Ws[nbase + nf * 16 + (lane & 15)][koff]);
            acc[nf] = __builtin_amdgcn_mfma_f32_16x16x32_f16(afrag, bfrag, acc[nf], 0, 0, 0);
        }
    }
    // C/D: col = lane&15, row = (lane>>4)*4 + reg [m89-verified]; permute cols
    int orow = row0 + (wv & 1) * 16 + (lane >> 4) * 4;
    int ocol = lane & 15;
#pragma unroll
    for (int nf = 0; nf < 5; nf++) {
        int col = nbase + nf * 16 + ocol;
        int dir = (col >= G4) ? 1 : 0;
        int g = col - dir * G4;
        int pcol = dir * G4 + (g % 40) * 2 + (g / 40);
#pragma unroll
        for (int r = 0; r < 4; r++)
            gpre[(size_t)(orow + r) * NOUT + pcol] = acc[nf][r];
    }
}

// ---------------- K3: recurrent LSTM, single-wave blocks, no barriers -------
__device__ __forceinline__ float fsig(float v) { return 1.f / (1.f + __expf(-v)); }
__device__ __forceinline__ float ftanh(float v) { return 2.f / (1.f + __expf(-2.f * v)) - 1.f; }

__global__ __launch_bounds__(64) void k_lstm(
    const float* __restrict__ gpre,
    const float* __restrict__ whh_f, const float* __restrict__ whh_b,
    const float* __restrict__ bias_f, const float* __restrict__ bias_b,
    float* __restrict__ out)
{
    int dir  = blockIdx.x >> 6;   // grid = 128
    int b    = blockIdx.x & 63;
    int lane = threadIdx.x;
    const float* whh  = dir ? whh_b  : whh_f;
    const float* bias = dir ? bias_b : bias_f;

    int g0 = (lane < 40) ? lane : 39;   // clamp idle lanes to valid memory
    int g1 = g0 + 40;
    float w0[HH], w1[HH];
#pragma unroll
    for (int k = 0; k < HH; k++) {
        w0[k] = whh[g0 * HH + k];
        w1[k] = whh[g1 * HH + k];
    }
    float b0 = bias[g0], b1 = bias[g1];

    // permuted gpre: lane j's (gate j, gate j+40) pair is contiguous float2
    const float* gp = gpre + (size_t)b * WW * NOUT + dir * G4 + g0 * 2;
    float h = 0.f, c = 0.f;             // live in lanes < 20
    int w = dir ? (WW - 1) : 0;
    int stepd = dir ? -1 : 1;
    float2 pre = *(const float2*)(gp + (size_t)w * NOUT);

    for (int s = 0; s < WW; ++s) {
        int wn = w + stepd;
        float2 nxt = make_float2(0.f, 0.f);
        if (s + 1 < WW)                 // prefetch next step (independent of h)
            nxt = *(const float2*)(gp + (size_t)wn * NOUT);
        float s00 = 0.f, s01 = 0.f, s10 = 0.f, s11 = 0.f;
#pragma unroll
        for (int k = 0; k < 10; k++) {
            float hv  = __shfl(h, k, 64);
            float hv2 = __shfl(h, k + 10, 64);
            s00 = fmaf(hv,  w0[k],      s00);
            s10 = fmaf(hv,  w1[k],      s10);
            s01 = fmaf(hv2, w0[k + 10], s01);
            s11 = fmaf(hv2, w1[k + 10], s11);
        }
        float a0 = pre.x + b0 + s00 + s01;
        float a1 = pre.y + b1 + s10 + s11;
        int src = (lane % 20) + 20;
        float fv = __shfl(a0, src, 64);
        float ov = __shfl(a1, src, 64);
        if (lane < HH) {
            c = fsig(fv) * c + fsig(a0) * ftanh(a1);
            h = fsig(ov) * ftanh(c);
            out[((size_t)b * WW + w) * (2 * HH) + dir * HH + lane] = h;
        }
        pre = nxt;
        w = wn;
    }
}

extern "C" void kernel_launch(void* const* d_in, const int* in_sizes, int n_in,
                              void* d_out, int out_size, void* d_ws, size_t ws_size,
                              hipStream_t stream) {
    const float* hiddens   = (const float*)d_in[0];
    const int*   bert2toks = (const int*)d_in[1];
    const int*   cap_inds  = (const int*)d_in[2];
    const float* cap_table = (const float*)d_in[3];
    const float* w_ih_f    = (const float*)d_in[4];
    const float* w_hh_f    = (const float*)d_in[5];
    const float* b_f       = (const float*)d_in[6];
    const float* w_ih_b    = (const float*)d_in[7];
    const float* w_hh_b    = (const float*)d_in[8];
    const float* b_b       = (const float*)d_in[9];
    float* out = (float*)d_out;

    _Float16* wpad = (_Float16*)((char*)d_ws + WP_OFF);
    int2*     seg  = (int2*)((char*)d_ws + SEG_OFF);
    float*    gpre = (float*)((char*)d_ws + GP_OFF);

    k_pad_w<<<NOUT, 256, 0, stream>>>(w_ih_f, w_ih_b, wpad);
    k_seg<<<BB, 256, 0, stream>>>(bert2toks, seg);
    k_fused<<<(BB * WW) / BMF, 256, 0, stream>>>(hiddens, seg, cap_inds, cap_table, wpad, gpre);
    k_lstm<<<128, 64, 0, stream>>>(gpre, w_hh_f, w_hh_b, b_f, b_b, out);
}

// Round 5
// 253.925 us; speedup vs baseline: 1.1341x; 1.1341x over previous
//
#include <hip/hip_runtime.h>
#include <math.h>

#define BB 64
#define T_SUB 512
#define WW 256
#define DD 768
#define HH 20
#define CAP_DIM 10
#define IN_DIM 778
#define KPAD 800
#define G4 80     // 4*H
#define NOUT 160  // both directions fused

typedef _Float16 f16x8 __attribute__((ext_vector_type(8)));
typedef _Float16 f16x4 __attribute__((ext_vector_type(4)));
typedef float f32x4 __attribute__((ext_vector_type(4)));

// ws layout (bytes):
//   wpad : [160][800] f16   @ 0          (256,000 B)
//   seg  : int2[16384]      @ 256,000    (131,072 B)
//   x    : [16384][800] f16 @ 387,072    (26,214,400 B)
//   gpre : [16384][160] f32 @ 26,601,472 (10,485,760 B) -- columns PERMUTED
#define WP_OFF   ((size_t)0)
#define SEG_OFF  ((size_t)256000)
#define X_OFF    ((size_t)387072)
#define GP_OFF   ((size_t)26601472)

// ---------------- K0: pad weights (blocks 0..159) + segment search (160..223)
__global__ __launch_bounds__(256) void k_prep(
    const float* __restrict__ wf, const float* __restrict__ wb,
    const int* __restrict__ b2t,
    _Float16* __restrict__ wp, int2* __restrict__ seg)
{
    int blk = blockIdx.x;
    if (blk < NOUT) {
        int j = blk;
        const float* src = (j < G4) ? (wf + (size_t)j * IN_DIM)
                                    : (wb + (size_t)(j - G4) * IN_DIM);
        for (int k = threadIdx.x; k < KPAD; k += 256)
            wp[(size_t)j * KPAD + k] = (k < IN_DIM) ? (_Float16)src[k] : (_Float16)0.f;
    } else {
        int b = blk - NOUT, w = threadIdx.x;
        const int* row = b2t + (size_t)b * T_SUB;
        int lo = 0, hi = T_SUB;
        while (lo < hi) { int m = (lo + hi) >> 1; if (row[m] < w) lo = m + 1; else hi = m; }
        int lo2 = lo, hi2 = T_SUB;
        while (lo2 < hi2) { int m = (lo2 + hi2) >> 1; if (row[m] < w + 1) lo2 = m + 1; else hi2 = m; }
        seg[(size_t)b * WW + w] = make_int2(lo, lo2 - lo);
    }
}

// ---------------- K1: streaming mean -> fp16 x. One thread per 4 output dims.
// idx = (b*WW + w)*200 + d4; d4<192: mean of 3 layers x cnt tokens; else caps.
__global__ __launch_bounds__(256) void k_mean(
    const float* __restrict__ hiddens, const int2* __restrict__ seg,
    const int* __restrict__ cap_inds, const float* __restrict__ cap_table,
    _Float16* __restrict__ x)
{
    int idx = blockIdx.x * 256 + threadIdx.x;   // 16384*200 total
    int d4 = idx % 200;
    int bw = idx / 200;
    int b = bw >> 8, w = bw & 255;
    f16x4 r;
    if (d4 < 192) {
        int2 sg = seg[bw];
        int lo = sg.x, cnt = sg.y;
        const size_t LSTR = (size_t)BB * (T_SUB + 1) * DD;
        const float* base = hiddens + ((size_t)b * (T_SUB + 1) + lo + 1) * DD + d4 * 4;
        float ax = 0.f, ay = 0.f, az = 0.f, aw = 0.f;
        if (cnt == 2) {
#pragma unroll
            for (int l = 0; l < 3; ++l) {
                float4 v0 = *(const float4*)(base + l * LSTR);
                float4 v1 = *(const float4*)(base + l * LSTR + DD);
                ax += v0.x + v1.x; ay += v0.y + v1.y;
                az += v0.z + v1.z; aw += v0.w + v1.w;
            }
        } else {
            for (int l = 0; l < 3; ++l)
                for (int ti = 0; ti < cnt; ++ti) {
                    float4 v = *(const float4*)(base + l * LSTR + (size_t)ti * DD);
                    ax += v.x; ay += v.y; az += v.z; aw += v.w;
                }
        }
        float inv = 1.0f / (3.0f * (float)(cnt > 0 ? cnt : 1));
        r[0] = (_Float16)(ax * inv); r[1] = (_Float16)(ay * inv);
        r[2] = (_Float16)(az * inv); r[3] = (_Float16)(aw * inv);
    } else {
        int ci = cap_inds[bw];
#pragma unroll
        for (int q = 0; q < 4; q++) {
            int c = (d4 - 192) * 4 + q;   // col 768+c
            r[q] = (c < CAP_DIM) ? (_Float16)cap_table[ci * CAP_DIM + c] : (_Float16)0.f;
        }
    }
    *(f16x4*)(x + (size_t)bw * KPAD + d4 * 4) = r;
}

// ---------------- K2: MFMA fp16 GEMM  gpre = x @ wpad^T (cols permuted) -----
// M=16384, K=800, N=160. Block tile 64x160, 4 waves (16 m-rows each), BK=32.
#define BMT 64
__global__ __launch_bounds__(256) void k_gemm(
    const _Float16* __restrict__ x, const _Float16* __restrict__ wp,
    float* __restrict__ gpre)
{
    __shared__ _Float16 As[BMT][40];
    __shared__ _Float16 Ws[NOUT][40];
    int t = threadIdx.x;
    int wv = t >> 6;
    int lane = t & 63;
    int row0 = blockIdx.x * BMT;
    f32x4 acc[10];
#pragma unroll
    for (int i = 0; i < 10; i++)
#pragma unroll
        for (int r = 0; r < 4; r++) acc[i][r] = 0.f;

    for (int k0 = 0; k0 < KPAD; k0 += 32) {
        __syncthreads();
        {   // stage A tile: 64 rows x 32 f16 (4 chunks of 16B) — 256 loads
            int r = t >> 2, ch = t & 3;
            float4 v = *(const float4*)(x + (size_t)(row0 + r) * KPAD + k0 + ch * 8);
            *(float4*)(&As[r][ch * 8]) = v;
        }
        for (int s = t; s < 640; s += 256) {   // stage W tile: 160x32
            int r = s >> 2, ch = s & 3;
            float4 v = *(const float4*)(wp + (size_t)r * KPAD + k0 + ch * 8);
            *(float4*)(&Ws[r][ch * 8]) = v;
        }
        __syncthreads();
        int arow = wv * 16 + (lane & 15);
        int koff = (lane >> 4) * 8;
        f16x8 afrag = *(const f16x8*)(&As[arow][koff]);
#pragma unroll
        for (int nf = 0; nf < 10; nf++) {
            f16x8 bfrag = *(const f16x8*)(&Ws[nf * 16 + (lane & 15)][koff]);
            acc[nf] = __builtin_amdgcn_mfma_f32_16x16x32_f16(afrag, bfrag, acc[nf], 0, 0, 0);
        }
    }
    // C/D: col = lane&15, row = (lane>>4)*4 + reg [m89-verified].
    // Permute cols so lstm lane j reads (gate j, gate j+40) as one float2:
    //   col dir*80+g -> dir*80 + (g%40)*2 + g/40
    int orow = row0 + wv * 16 + (lane >> 4) * 4;
    int ocol = lane & 15;
#pragma unroll
    for (int nf = 0; nf < 10; nf++) {
        int col = nf * 16 + ocol;
        int dir = (col >= G4) ? 1 : 0;
        int g = col - dir * G4;
        int pcol = dir * G4 + (g % 40) * 2 + (g / 40);
#pragma unroll
        for (int r = 0; r < 4; r++)
            gpre[(size_t)(orow + r) * NOUT + pcol] = acc[nf][r];
    }
}

// ---------------- K3: recurrent LSTM, single-wave blocks, no barriers -------
__device__ __forceinline__ float fsig(float v) { return 1.f / (1.f + __expf(-v)); }
__device__ __forceinline__ float ftanh(float v) { return 2.f / (1.f + __expf(-2.f * v)) - 1.f; }

__global__ __launch_bounds__(64) void k_lstm(
    const float* __restrict__ gpre,
    const float* __restrict__ whh_f, const float* __restrict__ whh_b,
    const float* __restrict__ bias_f, const float* __restrict__ bias_b,
    float* __restrict__ out)
{
    int dir  = blockIdx.x >> 6;   // grid = 128
    int b    = blockIdx.x & 63;
    int lane = threadIdx.x;
    const float* whh  = dir ? whh_b  : whh_f;
    const float* bias = dir ? bias_b : bias_f;

    int g0 = (lane < 40) ? lane : 39;   // clamp idle lanes to valid memory
    int g1 = g0 + 40;
    float w0[HH], w1[HH];
#pragma unroll
    for (int k = 0; k < HH; k++) {
        w0[k] = whh[g0 * HH + k];
        w1[k] = whh[g1 * HH + k];
    }
    float b0 = bias[g0], b1 = bias[g1];

    // permuted gpre: lane j's (gate j, gate j+40) pair is contiguous float2
    const float* gp = gpre + (size_t)b * WW * NOUT + dir * G4 + g0 * 2;
    float h = 0.f, c = 0.f;             // live in lanes < 20
    int w = dir ? (WW - 1) : 0;
    int stepd = dir ? -1 : 1;
    float2 pre = *(const float2*)(gp + (size_t)w * NOUT);

    for (int s = 0; s < WW; ++s) {
        int wn = w + stepd;
        float2 nxt = make_float2(0.f, 0.f);
        if (s + 1 < WW)                 // prefetch next step (independent of h)
            nxt = *(const float2*)(gp + (size_t)wn * NOUT);
        float s00 = 0.f, s01 = 0.f, s10 = 0.f, s11 = 0.f;
#pragma unroll
        for (int k = 0; k < 10; k++) {
            float hv  = __shfl(h, k, 64);
            float hv2 = __shfl(h, k + 10, 64);
            s00 = fmaf(hv,  w0[k],      s00);
            s10 = fmaf(hv,  w1[k],      s10);
            s01 = fmaf(hv2, w0[k + 10], s01);
            s11 = fmaf(hv2, w1[k + 10], s11);
        }
        float a0 = pre.x + b0 + s00 + s01;
        float a1 = pre.y + b1 + s10 + s11;
        int src = (lane % 20) + 20;
        float fv = __shfl(a0, src, 64);
        float ov = __shfl(a1, src, 64);
        if (lane < HH) {
            c = fsig(fv) * c + fsig(a0) * ftanh(a1);
            h = fsig(ov) * ftanh(c);
            out[((size_t)b * WW + w) * (2 * HH) + dir * HH + lane] = h;
        }
        pre = nxt;
        w = wn;
    }
}

extern "C" void kernel_launch(void* const* d_in, const int* in_sizes, int n_in,
                              void* d_out, int out_size, void* d_ws, size_t ws_size,
                              hipStream_t stream) {
    const float* hiddens   = (const float*)d_in[0];
    const int*   bert2toks = (const int*)d_in[1];
    const int*   cap_inds  = (const int*)d_in[2];
    const float* cap_table = (const float*)d_in[3];
    const float* w_ih_f    = (const float*)d_in[4];
    const float* w_hh_f    = (const float*)d_in[5];
    const float* b_f       = (const float*)d_in[6];
    const float* w_ih_b    = (const float*)d_in[7];
    const float* w_hh_b    = (const float*)d_in[8];
    const float* b_b       = (const float*)d_in[9];
    float* out = (float*)d_out;

    _Float16* wpad = (_Float16*)((char*)d_ws + WP_OFF);
    int2*     seg  = (int2*)((char*)d_ws + SEG_OFF);
    _Float16* x    = (_Float16*)((char*)d_ws + X_OFF);
    float*    gpre = (float*)((char*)d_ws + GP_OFF);

    k_prep<<<NOUT + BB, 256, 0, stream>>>(w_ih_f, w_ih_b, bert2toks, wpad, seg);
    k_mean<<<(BB * WW * 200) / 256, 256, 0, stream>>>(hiddens, seg, cap_inds, cap_table, x);
    k_gemm<<<(BB * WW) / BMT, 256, 0, stream>>>(x, wpad, gpre);
    k_lstm<<<128, 64, 0, stream>>>(gpre, w_hh_f, w_hh_b, b_f, b_b, out);
}

// Round 6
// 224.456 us; speedup vs baseline: 1.2830x; 1.1313x over previous
//
#include <hip/hip_runtime.h>
#include <math.h>

#define BB 64
#define T_SUB 512
#define WW 256
#define DD 768
#define HH 20
#define CAP_DIM 10
#define IN_DIM 778
#define KPAD 800
#define G4 80     // 4*H
#define NOUT 160  // both directions fused

typedef _Float16 f16x8 __attribute__((ext_vector_type(8)));
typedef _Float16 f16x4 __attribute__((ext_vector_type(4)));
typedef float f32x4 __attribute__((ext_vector_type(4)));

// ws layout (bytes):
//   wpad : [160][800] f16   @ 0          (256,000 B)
//   seg  : int2[16384]      @ 256,000    (131,072 B)
//   x    : [16384][800] f16 @ 387,072    (26,214,400 B)
//   gpre : [16384][160] f32 @ 26,601,472 (10,485,760 B) -- columns PERMUTED
#define WP_OFF   ((size_t)0)
#define SEG_OFF  ((size_t)256000)
#define X_OFF    ((size_t)387072)
#define GP_OFF   ((size_t)26601472)

// ---------------- K0: pad weights (blocks 0..159) + segment search (160..223)
__global__ __launch_bounds__(256) void k_prep(
    const float* __restrict__ wf, const float* __restrict__ wb,
    const int* __restrict__ b2t,
    _Float16* __restrict__ wp, int2* __restrict__ seg)
{
    int blk = blockIdx.x;
    if (blk < NOUT) {
        int j = blk;
        const float* src = (j < G4) ? (wf + (size_t)j * IN_DIM)
                                    : (wb + (size_t)(j - G4) * IN_DIM);
        for (int k = threadIdx.x; k < KPAD; k += 256)
            wp[(size_t)j * KPAD + k] = (k < IN_DIM) ? (_Float16)src[k] : (_Float16)0.f;
    } else {
        int b = blk - NOUT, w = threadIdx.x;
        const int* row = b2t + (size_t)b * T_SUB;
        int lo = 0, hi = T_SUB;
        while (lo < hi) { int m = (lo + hi) >> 1; if (row[m] < w) lo = m + 1; else hi = m; }
        int lo2 = lo, hi2 = T_SUB;
        while (lo2 < hi2) { int m = (lo2 + hi2) >> 1; if (row[m] < w + 1) lo2 = m + 1; else hi2 = m; }
        seg[(size_t)b * WW + w] = make_int2(lo, lo2 - lo);
    }
}

// ---------------- K1: streaming mean -> fp16 x. One thread per 4 output dims.
__global__ __launch_bounds__(256) void k_mean(
    const float* __restrict__ hiddens, const int2* __restrict__ seg,
    const int* __restrict__ cap_inds, const float* __restrict__ cap_table,
    _Float16* __restrict__ x)
{
    int idx = blockIdx.x * 256 + threadIdx.x;   // 16384*200 total
    int d4 = idx % 200;
    int bw = idx / 200;
    int b = bw >> 8;
    f16x4 r;
    if (d4 < 192) {
        int2 sg = seg[bw];
        int lo = sg.x, cnt = sg.y;
        const size_t LSTR = (size_t)BB * (T_SUB + 1) * DD;
        const float* base = hiddens + ((size_t)b * (T_SUB + 1) + lo + 1) * DD + d4 * 4;
        float ax = 0.f, ay = 0.f, az = 0.f, aw = 0.f;
        if (cnt == 2) {
#pragma unroll
            for (int l = 0; l < 3; ++l) {
                float4 v0 = *(const float4*)(base + l * LSTR);
                float4 v1 = *(const float4*)(base + l * LSTR + DD);
                ax += v0.x + v1.x; ay += v0.y + v1.y;
                az += v0.z + v1.z; aw += v0.w + v1.w;
            }
        } else {
            for (int l = 0; l < 3; ++l)
                for (int ti = 0; ti < cnt; ++ti) {
                    float4 v = *(const float4*)(base + l * LSTR + (size_t)ti * DD);
                    ax += v.x; ay += v.y; az += v.z; aw += v.w;
                }
        }
        float inv = 1.0f / (3.0f * (float)(cnt > 0 ? cnt : 1));
        r[0] = (_Float16)(ax * inv); r[1] = (_Float16)(ay * inv);
        r[2] = (_Float16)(az * inv); r[3] = (_Float16)(aw * inv);
    } else {
        int ci = cap_inds[bw];
#pragma unroll
        for (int q = 0; q < 4; q++) {
            int c = (d4 - 192) * 4 + q;   // col 768+c
            r[q] = (c < CAP_DIM) ? (_Float16)cap_table[ci * CAP_DIM + c] : (_Float16)0.f;
        }
    }
    *(f16x4*)(x + (size_t)bw * KPAD + d4 * 4) = r;
}

// ---------------- K2: barrier-free MFMA fp16 GEMM, operands from global -----
// Each wave: 16 rows x 160 cols, K=800. Register ping-pong double buffer.
#define LOADAB(A, Bv, K0) do {                                                  \
    A = *(const f16x8*)(ap + (K0));                                             \
    _Pragma("unroll")                                                           \
    for (int nf = 0; nf < 10; nf++)                                             \
        Bv[nf] = *(const f16x8*)(bp + (size_t)nf * 16 * KPAD + (K0));           \
} while (0)
#define DOMFMA(A, Bv) do {                                                      \
    _Pragma("unroll")                                                           \
    for (int nf = 0; nf < 10; nf++)                                             \
        acc[nf] = __builtin_amdgcn_mfma_f32_16x16x32_f16(A, Bv[nf], acc[nf], 0, 0, 0); \
} while (0)

__global__ __launch_bounds__(256) void k_gemm(
    const _Float16* __restrict__ x, const _Float16* __restrict__ wp,
    float* __restrict__ gpre)
{
    int t = threadIdx.x, wv = t >> 6, lane = t & 63;
    int row  = blockIdx.x * 64 + wv * 16 + (lane & 15);
    int koff = (lane >> 4) * 8;
    const _Float16* ap = x + (size_t)row * KPAD + koff;
    const _Float16* bp = wp + (size_t)(lane & 15) * KPAD + koff;
    f32x4 acc[10];
#pragma unroll
    for (int i = 0; i < 10; i++)
#pragma unroll
        for (int r = 0; r < 4; r++) acc[i][r] = 0.f;

    f16x8 a0v, a1v, b0v[10], b1v[10];
    LOADAB(a0v, b0v, 0);
    int k0 = 0;
    for (int it = 0; it < 12; ++it, k0 += 64) {
        LOADAB(a1v, b1v, k0 + 32);
        DOMFMA(a0v, b0v);
        LOADAB(a0v, b0v, k0 + 64);
        DOMFMA(a1v, b1v);
    }
    DOMFMA(a0v, b0v);   // k0 == 768 chunk (loaded inside last iteration)

    // C/D: col = lane&15, row = (lane>>4)*4 + reg [m89-verified].
    // Permute cols so lstm lane j reads (gate j, gate j+40) as one float2:
    //   col dir*80+g -> dir*80 + (g%40)*2 + g/40
    int orow = blockIdx.x * 64 + wv * 16 + (lane >> 4) * 4;
    int ocol = lane & 15;
#pragma unroll
    for (int nf = 0; nf < 10; nf++) {
        int col = nf * 16 + ocol;
        int dir = (col >= G4) ? 1 : 0;
        int g = col - dir * G4;
        int pcol = dir * G4 + (g % 40) * 2 + (g / 40);
#pragma unroll
        for (int r = 0; r < 4; r++)
            gpre[(size_t)(orow + r) * NOUT + pcol] = acc[nf][r];
    }
}

// ---------------- K3: recurrent LSTM, LDS-staged gpre, chunked ping-pong ----
// grid = 128 (dir*64 + b), block = 256 (4 waves). Wave 0 computes; waves 1-3
// stage the next 64-step chunk of gpre into LDS during the current chunk.
__device__ __forceinline__ float fsig(float v) { return 1.f / (1.f + __expf(-v)); }
__device__ __forceinline__ float ftanh(float v) { return 2.f / (1.f + __expf(-2.f * v)) - 1.f; }

__global__ __launch_bounds__(256) void k_lstm(
    const float* __restrict__ gpre,
    const float* __restrict__ whh_f, const float* __restrict__ whh_b,
    const float* __restrict__ bias_f, const float* __restrict__ bias_b,
    float* __restrict__ out)
{
    __shared__ float gbuf[2][64 * G4];   // 2 x 20 KB ping-pong
    int dir  = blockIdx.x >> 6;
    int b    = blockIdx.x & 63;
    int t    = threadIdx.x;
    int wv   = t >> 6;
    int lane = t & 63;
    const float* gsrc = gpre + (size_t)b * WW * NOUT + dir * G4;  // 80-float slice per row

    // initial stage: chunk 0 into buf 0 (all 4 waves; 1280 float4 items)
    {
        int base = dir ? 192 : 0;
        for (int f = t; f < 1280; f += 256) {
            int row = f / 20, q = f % 20;
            float4 v = *(const float4*)(gsrc + (size_t)(base + row) * NOUT + q * 4);
            *(float4*)(&gbuf[0][row * G4 + q * 4]) = v;
        }
    }

    const float* whh  = dir ? whh_b  : whh_f;
    const float* bias = dir ? bias_b : bias_f;
    int g0 = (lane < 40) ? lane : 39;
    int g1 = g0 + 40;
    float w0[HH], w1[HH], b0 = 0.f, b1 = 0.f;
    if (wv == 0) {
#pragma unroll
        for (int k = 0; k < HH; k++) {
            w0[k] = whh[g0 * HH + k];
            w1[k] = whh[g1 * HH + k];
        }
        b0 = bias[g0]; b1 = bias[g1];
    }
    __syncthreads();

    float h = 0.f, c = 0.f;
    int w = dir ? (WW - 1) : 0;
    int stepd = dir ? -1 : 1;

    for (int ch = 0; ch < 4; ++ch) {
        int cb = ch & 1;
        if (wv > 0) {
            if (ch + 1 < 4) {       // stage next chunk into the other buffer
                int nbase = dir ? (192 - (ch + 1) * 64) : (ch + 1) * 64;
                for (int f = t - 64; f < 1280; f += 192) {
                    int row = f / 20, q = f % 20;
                    float4 v = *(const float4*)(gsrc + (size_t)(nbase + row) * NOUT + q * 4);
                    *(float4*)(&gbuf[cb ^ 1][row * G4 + q * 4]) = v;
                }
            }
        } else {
            int base = dir ? (192 - ch * 64) : ch * 64;
            float2 pre = *(const float2*)(&gbuf[cb][(w - base) * G4 + g0 * 2]);
            for (int sl = 0; sl < 64; ++sl) {
                int wn = w + stepd;
                float2 nxt = make_float2(0.f, 0.f);
                if (sl < 63)        // prefetch within chunk only (next chunk not ready)
                    nxt = *(const float2*)(&gbuf[cb][(wn - base) * G4 + g0 * 2]);
                float s00 = 0.f, s01 = 0.f, s10 = 0.f, s11 = 0.f;
#pragma unroll
                for (int k = 0; k < 10; k++) {
                    float hv  = __shfl(h, k, 64);
                    float hv2 = __shfl(h, k + 10, 64);
                    s00 = fmaf(hv,  w0[k],      s00);
                    s10 = fmaf(hv,  w1[k],      s10);
                    s01 = fmaf(hv2, w0[k + 10], s01);
                    s11 = fmaf(hv2, w1[k + 10], s11);
                }
                float a0 = pre.x + b0 + s00 + s01;
                float a1 = pre.y + b1 + s10 + s11;
                int src = (lane % 20) + 20;
                float fv = __shfl(a0, src, 64);
                float ov = __shfl(a1, src, 64);
                if (lane < HH) {
                    c = fsig(fv) * c + fsig(a0) * ftanh(a1);
                    h = fsig(ov) * ftanh(c);
                    out[((size_t)b * WW + w) * (2 * HH) + dir * HH + lane] = h;
                }
                pre = nxt;
                w = wn;
            }
        }
        __syncthreads();
    }
}

extern "C" void kernel_launch(void* const* d_in, const int* in_sizes, int n_in,
                              void* d_out, int out_size, void* d_ws, size_t ws_size,
                              hipStream_t stream) {
    const float* hiddens   = (const float*)d_in[0];
    const int*   bert2toks = (const int*)d_in[1];
    const int*   cap_inds  = (const int*)d_in[2];
    const float* cap_table = (const float*)d_in[3];
    const float* w_ih_f    = (const float*)d_in[4];
    const float* w_hh_f    = (const float*)d_in[5];
    const float* b_f       = (const float*)d_in[6];
    const float* w_ih_b    = (const float*)d_in[7];
    const float* w_hh_b    = (const float*)d_in[8];
    const float* b_b       = (const float*)d_in[9];
    float* out = (float*)d_out;

    _Float16* wpad = (_Float16*)((char*)d_ws + WP_OFF);
    int2*     seg  = (int2*)((char*)d_ws + SEG_OFF);
    _Float16* x    = (_Float16*)((char*)d_ws + X_OFF);
    float*    gpre = (float*)((char*)d_ws + GP_OFF);

    k_prep<<<NOUT + BB, 256, 0, stream>>>(w_ih_f, w_ih_b, bert2toks, wpad, seg);
    k_mean<<<(BB * WW * 200) / 256, 256, 0, stream>>>(hiddens, seg, cap_inds, cap_table, x);
    k_gemm<<<(BB * WW) / 64, 256, 0, stream>>>(x, wpad, gpre);
    k_lstm<<<128, 256, 0, stream>>>(gpre, w_hh_f, w_hh_b, b_f, b_b, out);
}